// Round 5
// baseline (188.607 us; speedup 1.0000x reference)
//
#include <hip/hip_runtime.h>

#define NUM_HEADS 16
#define HEAD_DIM  128
#define SEQ       2048
#define BQ        64
#define BK        64
#define KSTRIDE   136   // ushorts: 128 + 8 pad
#define VSTRIDE   72    // ushorts: 64 + 8 pad (16B-aligned rows)
#define PSTRIDE   68    // ushorts: 64 + 4 pad (8B-aligned rows, bank-spread)

typedef __attribute__((ext_vector_type(8))) unsigned short us8;
typedef __attribute__((ext_vector_type(4))) unsigned short us4;
typedef __attribute__((ext_vector_type(8))) __bf16 bf16x8;
typedef __attribute__((ext_vector_type(4))) float f32x4;
typedef __attribute__((ext_vector_type(4))) unsigned u32x4;

static __device__ inline unsigned short f2bf(float x) {   // RNE
    union { float f; unsigned u; } v; v.f = x;
    unsigned r = v.u + 0x7FFFu + ((v.u >> 16) & 1u);
    return (unsigned short)(r >> 16);
}
static __device__ inline float bf2f(unsigned short h) {
    union { float f; unsigned u; } v; v.u = ((unsigned)h) << 16;
    return v.f;
}
static __device__ inline unsigned pk2bf(float a, float b) {
    return (unsigned)f2bf(a) | ((unsigned)f2bf(b) << 16);
}
static __device__ inline f32x4 mfma16(us8 a, us8 b, f32x4 c) {
    return __builtin_amdgcn_mfma_f32_16x16x32_bf16(
        __builtin_bit_cast(bf16x8, a), __builtin_bit_cast(bf16x8, b), c, 0, 0, 0);
}

__global__ __launch_bounds__(256, 3)
void diff_attn_mfma3(const float* __restrict__ Q,
                     const float* __restrict__ K,
                     const float* __restrict__ V,
                     float* __restrict__ Out)
{
    __shared__ __align__(16) unsigned short Khi[BK][KSTRIDE];          // 17408 B
    __shared__ __align__(16) unsigned short Vt[HEAD_DIM][VSTRIDE];     // 18432 B
    __shared__ __align__(16) unsigned short Pw[4][2][16][PSTRIDE];     // 17408 B -> 53248 B total

    const int t    = (int)threadIdx.x;
    const int wv   = t >> 6;        // 0..3, wave owns q-rows wv*16..+15 (full k, full dims)
    const int ln   = t & 63;
    const int l15  = ln & 15;
    const int quad = ln >> 4;

    // causal load balance: blocks b and b+256 pair q-tiles (i, 31-i)
    const int bx  = (int)blockIdx.x;
    const int h   = bx & 15;
    const int idx = bx >> 4;                  // 0..31
    const int qt  = (idx < 16) ? idx : 47 - idx;
    const int kvh = h >> 2;
    const int q0  = qt * BQ;

    const float* Qb = Q + (size_t)h   * SEQ * HEAD_DIM;
    const float* Kb = K + (size_t)kvh * SEQ * HEAD_DIM;
    const float* Vb = V + (size_t)kvh * SEQ * HEAD_DIM;

    // ---- Q fragments in registers (hi/lo bf16 split; scaled by 1/8 exactly) ----
    us8 qhi[2][2], qlo[2][2];   // [half][k-chunk-of-32]
    {
        const float* qr = Qb + (size_t)(q0 + wv * 16 + l15) * HEAD_DIM;
        #pragma unroll
        for (int hf = 0; hf < 2; ++hf)
            #pragma unroll
            for (int kc = 0; kc < 2; ++kc) {
                const int d0 = hf * 64 + kc * 32 + quad * 8;
                float x[8];
                *(float4*)&x[0] = *(const float4*)(qr + d0);
                *(float4*)&x[4] = *(const float4*)(qr + d0 + 4);
                us8 hi8, lo8;
                #pragma unroll
                for (int j = 0; j < 8; ++j) {
                    float xs = x[j] * 0.125f;
                    unsigned short hb = f2bf(xs);
                    hi8[j] = hb;
                    lo8[j] = f2bf(xs - bf2f(hb));
                }
                qhi[hf][kc] = hi8; qlo[hf][kc] = lo8;
            }
    }

    f32x4 o1[8], o2[8];          // rows wv*16+quad*4+rg, dims dt*16+l15
    #pragma unroll
    for (int i = 0; i < 8; ++i) { o1[i] = (f32x4)0.f; o2[i] = (f32x4)0.f; }
    float rs1[4] = {0.f,0.f,0.f,0.f}, rs2[4] = {0.f,0.f,0.f,0.f};

    unsigned short* Pp1 = &Pw[wv][0][0][0];
    unsigned short* Pp2 = &Pw[wv][1][0][0];

    for (int kt = 0; kt <= qt; ++kt) {
        __syncthreads();   // all waves done reading Khi/Vt from prev iter

        // ---- stage K -> Khi (row-major bf16), 32 elems/thread via 4 b128 writes
        {
            const float* kb = Kb + (size_t)kt * BK * HEAD_DIM;
            #pragma unroll
            for (int i = 0; i < 4; ++i) {
                const int flat8 = t * 8 + i * 2048;
                const int r = flat8 >> 7, d = flat8 & 127;
                float x[8];
                *(float4*)&x[0] = *(const float4*)(kb + (size_t)r * HEAD_DIM + d);
                *(float4*)&x[4] = *(const float4*)(kb + (size_t)r * HEAD_DIM + d + 4);
                u32x4 pk;
                #pragma unroll
                for (int j = 0; j < 4; ++j) pk[j] = pk2bf(x[2*j], x[2*j+1]);
                *(us8*)&Khi[r][d] = __builtin_bit_cast(us8, pk);
            }
        }
        // ---- stage V -> Vt (transposed bf16): thread covers dim d, k-half kh
        {
            const float* vb = Vb + (size_t)kt * BK * HEAD_DIM;
            const int d = t & 127, kh = t >> 7;   // kh 0..1
            float col[32];
            #pragma unroll
            for (int k = 0; k < 32; ++k)
                col[k] = vb[(size_t)(kh * 32 + k) * HEAD_DIM + d];
            #pragma unroll
            for (int blk = 0; blk < 4; ++blk) {
                u32x4 pk;
                #pragma unroll
                for (int j = 0; j < 4; ++j) pk[j] = pk2bf(col[blk*8 + 2*j], col[blk*8 + 2*j + 1]);
                *(us8*)&Vt[d][kh * 32 + blk * 8] = __builtin_bit_cast(us8, pk);
            }
        }
        __syncthreads();   // staging visible

        // ---- scores (full k-range) + in-register softmax + wave-private P ----
        #pragma unroll
        for (int c4 = 0; c4 < 4; ++c4) {
            f32x4 s1 = (f32x4)0.f, s2 = (f32x4)0.f;
            #pragma unroll
            for (int kc = 0; kc < 2; ++kc) {
                us8 b1 = *(const us8*)&Khi[c4 * 16 + l15][kc * 32 + quad * 8];
                us8 b2 = *(const us8*)&Khi[c4 * 16 + l15][64 + kc * 32 + quad * 8];
                s1 = mfma16(qhi[0][kc], b1, s1);
                s1 = mfma16(qlo[0][kc], b1, s1);
                s2 = mfma16(qhi[1][kc], b2, s2);
                s2 = mfma16(qlo[1][kc], b2, s2);
            }
            const int colg  = kt * BK + c4 * 16 + l15;
            const int rbase = quad * 4;
            #pragma unroll
            for (int rg = 0; rg < 4; ++rg) {
                const bool ok = colg <= (q0 + wv * 16 + rbase + rg);   // causal
                float e1 = ok ? __expf(s1[rg]) : 0.f;
                float e2 = ok ? __expf(s2[rg]) : 0.f;
                unsigned short p1 = (unsigned short)(__builtin_bit_cast(unsigned, e1) >> 16);
                unsigned short p2 = (unsigned short)(__builtin_bit_cast(unsigned, e2) >> 16);
                rs1[rg] += bf2f(p1);
                rs2[rg] += bf2f(p2);
                Pp1[(rbase + rg) * PSTRIDE + c4 * 16 + l15] = p1;
                Pp2[(rbase + rg) * PSTRIDE + c4 * 16 + l15] = p2;
            }
        }

        // wave-private P: drain this wave's LDS writes, no workgroup barrier
        asm volatile("s_waitcnt lgkmcnt(0)" ::: "memory");

        // ---- PV: O += P * V  (full dim-range) ----
        #pragma unroll
        for (int c2 = 0; c2 < 2; ++c2) {
            const unsigned short* pp1 = &Pp1[l15 * PSTRIDE + c2 * 32 + quad * 8];
            const unsigned short* pp2 = &Pp2[l15 * PSTRIDE + c2 * 32 + quad * 8];
            us4 a1l = *(const us4*)pp1, a1h = *(const us4*)(pp1 + 4);
            us4 a2l = *(const us4*)pp2, a2h = *(const us4*)(pp2 + 4);
            us8 a1, a2;
            #pragma unroll
            for (int j = 0; j < 4; ++j) { a1[j] = a1l[j]; a1[4+j] = a1h[j];
                                          a2[j] = a2l[j]; a2[4+j] = a2h[j]; }
            #pragma unroll
            for (int dt = 0; dt < 8; ++dt) {
                us8 bv = *(const us8*)&Vt[dt * 16 + l15][c2 * 32 + quad * 8];
                o1[dt] = mfma16(a1, bv, o1[dt]);
                o2[dt] = mfma16(a2, bv, o2[dt]);
            }
        }
    }

    // ---- epilogue: reduce row sums over the 16-lane groups, normalize, write ----
    #pragma unroll
    for (int m = 1; m < 16; m <<= 1)
        #pragma unroll
        for (int rg = 0; rg < 4; ++rg) {
            rs1[rg] += __shfl_xor(rs1[rg], m, 64);
            rs2[rg] += __shfl_xor(rs2[rg], m, 64);
        }

    float* ob = Out + ((size_t)h * SEQ + q0) * HEAD_DIM;
    #pragma unroll
    for (int rg = 0; rg < 4; ++rg) {
        const int row = wv * 16 + quad * 4 + rg;
        const float il1 = 1.0f / rs1[rg];
        const float il2 = 1.0f / rs2[rg];
        #pragma unroll
        for (int dt = 0; dt < 8; ++dt) {
            ob[(size_t)row * HEAD_DIM + dt * 16 + l15] =
                0.2f * (o1[dt][rg] * il1 - 0.8f * o2[dt][rg] * il2);
        }
    }
}

extern "C" void kernel_launch(void* const* d_in, const int* in_sizes, int n_in,
                              void* d_out, int out_size, void* d_ws, size_t ws_size,
                              hipStream_t stream) {
    const float* Q = (const float*)d_in[0];
    const float* K = (const float*)d_in[1];
    const float* V = (const float*)d_in[2];
    float* Out = (float*)d_out;

    dim3 grid(512);      // 32 q-tiles x 16 heads, pairing-swizzled
    dim3 block(256);
    diff_attn_mfma3<<<grid, block, 0, stream>>>(Q, K, V, Out);
}

// Round 6
// 126.937 us; speedup vs baseline: 1.4858x; 1.4858x over previous
//
#include <hip/hip_runtime.h>

#define NUM_HEADS 16
#define HEAD_DIM  128
#define SEQ       2048

typedef __attribute__((ext_vector_type(8))) unsigned short us8;
typedef __attribute__((ext_vector_type(8))) __bf16 bf16x8;
typedef __attribute__((ext_vector_type(4))) float f32x4;
typedef __attribute__((ext_vector_type(4))) unsigned u32x4;
typedef __attribute__((ext_vector_type(2))) unsigned u32x2;

static __device__ inline unsigned short f2bf(float x) {   // RNE
    union { float f; unsigned u; } v; v.f = x;
    unsigned r = v.u + 0x7FFFu + ((v.u >> 16) & 1u);
    return (unsigned short)(r >> 16);
}
static __device__ inline float bf2f(unsigned short h) {
    union { float f; unsigned u; } v; v.u = ((unsigned)h) << 16;
    return v.f;
}
static __device__ inline unsigned pk2bf(float a, float b) {
    return (unsigned)f2bf(a) | ((unsigned)f2bf(b) << 16);
}
static __device__ inline f32x4 mfma16(us8 a, us8 b, f32x4 c) {
    return __builtin_amdgcn_mfma_f32_16x16x32_bf16(
        __builtin_bit_cast(bf16x8, a), __builtin_bit_cast(bf16x8, b), c, 0, 0, 0);
}

// ---------- pre-pass: K -> bf16 row-major; V -> bf16 transposed per 64-tile ----------
__global__ __launch_bounds__(256)
void prep_kv(const float* __restrict__ K, const float* __restrict__ V,
             unsigned short* __restrict__ Kbf, unsigned short* __restrict__ Vtb)
{
    const int bx = (int)blockIdx.x, t = (int)threadIdx.x;
    __shared__ __align__(16) float Ls[64][130];
    if (bx < 512) {
        // K convert: 4*2048*128 = 1,048,576 elems; 512*256 threads * 8 elems
        const size_t base = ((size_t)bx * 256 + t) * 8;
        float x[8];
        *(float4*)&x[0] = *(const float4*)(K + base);
        *(float4*)&x[4] = *(const float4*)(K + base + 4);
        u32x4 pk;
        #pragma unroll
        for (int j = 0; j < 4; ++j) pk[j] = pk2bf(x[2*j], x[2*j+1]);
        *(us8*)(Kbf + base) = __builtin_bit_cast(us8, pk);
    } else {
        // V transpose: block per (kvh, tile64): Vt[kvh][tile][128 dims][64 k]
        const int b2 = bx - 512, kvh = b2 >> 5, tile = b2 & 31;
        const float* vb = V + ((size_t)kvh * SEQ + tile * 64) * HEAD_DIM;
        #pragma unroll
        for (int i = 0; i < 8; ++i) {
            const int idx = t + i * 256;           // 0..2047 float4s
            const int r = idx >> 5, c4 = idx & 31;
            *(float4*)&Ls[r][c4 * 4] = *(const float4*)(vb + (size_t)r * HEAD_DIM + c4 * 4);
        }
        __syncthreads();
        const int d = t & 127, kh = t >> 7;
        unsigned pk[16];
        #pragma unroll
        for (int j = 0; j < 16; ++j)
            pk[j] = pk2bf(Ls[kh * 32 + 2*j][d], Ls[kh * 32 + 2*j + 1][d]);
        unsigned short* dst = Vtb + ((size_t)(kvh * 32 + tile) * 128 + d) * 64 + kh * 32;
        #pragma unroll
        for (int blk = 0; blk < 4; ++blk)
            *(us8*)(dst + blk * 8) = *(us8*)&pk[blk * 4];
    }
}

// ---------- main: flash diff-attn, S^T MFMA, async staging ----------
// smem: Ks [64 k][128 d] bf16 swizzled (16384) | Vts [128 d][64 k] bf16 swizzled (16384)
//       | P [4 waves][16 q][72 k] bf16 (9216)   -> 41984 B, 3 blocks/CU
#define KS_OFF 0
#define VT_OFF 16384
#define P_OFF  32768

__global__ __launch_bounds__(256, 3)
void diff_attn_mfma4(const float* __restrict__ Q,
                     const unsigned short* __restrict__ Kbf,
                     const unsigned short* __restrict__ Vtb,
                     float* __restrict__ Out)
{
    __shared__ __align__(16) unsigned char smem[41984];

    const int t    = (int)threadIdx.x;
    const int wv   = t >> 6;
    const int ln   = t & 63;
    const int l15  = ln & 15;
    const int quad = ln >> 4;
    const int mat  = wv >> 1;      // 0: softmax1 (dims 0..63), 1: softmax2 (dims 64..127)
    const int rfh  = wv & 1;       // rows rfh*16..+15 of the 32-row q-tile

    // grid 1024 = 16 h x 64 q-tiles(32 rows); idx pairing balances causal work
    const int bx  = (int)blockIdx.x;
    const int h   = bx & 15;
    const int idx = bx >> 4;                    // 0..63
    const int qt  = (idx < 32) ? idx : 95 - idx;
    const int kvh = h >> 2;
    const int q0  = qt * 32;
    const int nkt = (qt >> 1) + 1;

    // ---- Q fragment (B-operand layout: lane n=l15 q-row, k=quad*8+j), hi/lo split ----
    us8 qhi[2], qlo[2];
    {
        const float* qr = Q + ((size_t)h * SEQ + q0 + rfh * 16 + l15) * HEAD_DIM + mat * 64;
        #pragma unroll
        for (int kc = 0; kc < 2; ++kc) {
            const int d0 = kc * 32 + quad * 8;
            float x[8];
            *(float4*)&x[0] = *(const float4*)(qr + d0);
            *(float4*)&x[4] = *(const float4*)(qr + d0 + 4);
            us8 hi8, lo8;
            #pragma unroll
            for (int j = 0; j < 8; ++j) {
                float xs = x[j] * 0.125f;
                unsigned short hb = f2bf(xs);
                hi8[j] = hb;
                lo8[j] = f2bf(xs - bf2f(hb));
            }
            qhi[kc] = hi8; qlo[kc] = lo8;
        }
    }

    f32x4 o[8];                    // O^T frags: dim = dt*16+quad*4+rg, q-row = l15
    #pragma unroll
    for (int i = 0; i < 8; ++i) o[i] = (f32x4)0.f;
    float rs = 0.f;

    const unsigned short* Kt0 = Kbf + (size_t)kvh * SEQ * HEAD_DIM;
    const unsigned short* Vt0 = Vtb + (size_t)kvh * 32 * 128 * 64;
    unsigned char* Pp = smem + P_OFF + wv * 2304;   // wave-private P [16][72] ushorts

    for (int kt = 0; kt < nkt; ++kt) {
        __syncthreads();   // all waves done reading Ks/Vts of prev iter

        // ---- async staging: K tile (swizzled chunks), 4x16B per thread ----
        #pragma unroll
        for (int i = 0; i < 4; ++i) {
            const int L  = i * 256 + wv * 64 + ln;          // LDS chunk id
            const int r  = L >> 4;
            const int ch = (L & 15) ^ (r & 15);             // global chunk (un-swizzle)
            const unsigned short* g = Kt0 + (size_t)(kt * 64 + r) * 128 + ch * 8;
            __builtin_amdgcn_global_load_lds(
                (const __attribute__((address_space(1))) unsigned*)g,
                (__attribute__((address_space(3))) unsigned*)(smem + KS_OFF + (i * 256 + wv * 64) * 16),
                16, 0, 0);
        }
        // ---- async staging: Vt tile (swizzled chunks) ----
        #pragma unroll
        for (int i = 0; i < 4; ++i) {
            const int L  = i * 256 + wv * 64 + ln;
            const int r  = L >> 3;
            const int ch = (L & 7) ^ (r & 7);
            const unsigned short* g = Vt0 + (size_t)(kt * 128 + r) * 64 + ch * 8;
            __builtin_amdgcn_global_load_lds(
                (const __attribute__((address_space(1))) unsigned*)g,
                (__attribute__((address_space(3))) unsigned*)(smem + VT_OFF + (i * 256 + wv * 64) * 16),
                16, 0, 0);
        }
        __syncthreads();   // vmcnt(0) drained by barrier; staged data visible

        // ---- scores S^T = K . Q^T (A = K frag, B = Q frag) + exp + pack P ----
        #pragma unroll
        for (int c4 = 0; c4 < 4; ++c4) {
            f32x4 s = (f32x4)0.f;
            #pragma unroll
            for (int kc = 0; kc < 2; ++kc) {
                const int r  = c4 * 16 + l15;
                const int ch = (mat * 8 + kc * 4 + quad) ^ l15;
                us8 ak = *(const us8*)(smem + KS_OFF + r * 256 + ch * 16);
                s = mfma16(ak, qhi[kc], s);
                s = mfma16(ak, qlo[kc], s);
            }
            const int kg0 = kt * 64 + c4 * 16 + quad * 4;
            const int qg  = q0 + rfh * 16 + l15;
            unsigned tr[4];
            #pragma unroll
            for (int rg = 0; rg < 4; ++rg) {
                const bool ok = (kg0 + rg) <= qg;           // causal
                float ev = ok ? __expf(s[rg]) : 0.f;
                tr[rg] = __builtin_bit_cast(unsigned, ev) & 0xffff0000u;
                rs += __builtin_bit_cast(float, tr[rg]);    // denom from quantized P
            }
            u32x2 pw;
            pw[0] = (tr[0] >> 16) | tr[1];
            pw[1] = (tr[2] >> 16) | tr[3];
            *(u32x2*)(Pp + l15 * 144 + c4 * 32 + quad * 8) = pw;
        }

        // wave-private P: drain own LDS ops only, no block barrier
        asm volatile("s_waitcnt lgkmcnt(0)" ::: "memory");

        // ---- PV: O^T = V^T . P^T (A = Vt frag, B = P frag) ----
        #pragma unroll
        for (int c2 = 0; c2 < 2; ++c2) {
            us8 bp = *(const us8*)(Pp + l15 * 144 + c2 * 64 + quad * 16);
            #pragma unroll
            for (int dt = 0; dt < 8; ++dt) {
                const int r  = dt * 16 + l15;
                const int ch = (c2 * 4 + quad) ^ (r & 7);
                us8 av = *(const us8*)(smem + VT_OFF + r * 128 + ch * 16);
                o[dt] = mfma16(av, bp, o[dt]);
            }
        }
    }

    __syncthreads();   // all LDS reads done; smem reusable for combine

    // row sum: reduce partials across the 4 quads
    rs += __shfl_xor(rs, 16, 64);
    rs += __shfl_xor(rs, 32, 64);
    const float inv = 1.0f / rs;

    float* Cb = (float*)smem;   // [32 rows][132] combine buffer (16896 B)
    if (mat == 1) {
        #pragma unroll
        for (int dt = 0; dt < 8; ++dt) {
            f32x4 v;
            #pragma unroll
            for (int rg = 0; rg < 4; ++rg) v[rg] = o[dt][rg] * inv;
            *(f32x4*)(Cb + (rfh * 16 + l15) * 132 + dt * 16 + quad * 4) = v;
        }
    }
    __syncthreads();
    if (mat == 0) {
        float* ob = Out + ((size_t)h * SEQ + q0 + rfh * 16 + l15) * HEAD_DIM;
        #pragma unroll
        for (int dt = 0; dt < 8; ++dt) {
            const float* cb = Cb + (rfh * 16 + l15) * 132 + dt * 16 + quad * 4;
            float4 r;
            r.x = 0.2f * (o[dt][0] * inv) - 0.16f * cb[0];
            r.y = 0.2f * (o[dt][1] * inv) - 0.16f * cb[1];
            r.z = 0.2f * (o[dt][2] * inv) - 0.16f * cb[2];
            r.w = 0.2f * (o[dt][3] * inv) - 0.16f * cb[3];
            *(float4*)(ob + dt * 16 + quad * 4) = r;
        }
    }
}

extern "C" void kernel_launch(void* const* d_in, const int* in_sizes, int n_in,
                              void* d_out, int out_size, void* d_ws, size_t ws_size,
                              hipStream_t stream) {
    const float* Q = (const float*)d_in[0];
    const float* K = (const float*)d_in[1];
    const float* V = (const float*)d_in[2];
    float* Out = (float*)d_out;

    unsigned short* Kbf = (unsigned short*)d_ws;             // 2 MB
    unsigned short* Vtb = Kbf + (size_t)4 * SEQ * HEAD_DIM;  // 2 MB

    prep_kv<<<640, 256, 0, stream>>>(K, V, Kbf, Vtb);
    diff_attn_mfma4<<<1024, 256, 0, stream>>>(Q, Kbf, Vtb, Out);
}

// Round 7
// 124.836 us; speedup vs baseline: 1.5108x; 1.0168x over previous
//
#include <hip/hip_runtime.h>

#define NUM_HEADS 16
#define HEAD_DIM  128
#define SEQ       2048

typedef __attribute__((ext_vector_type(8))) unsigned short us8;
typedef __attribute__((ext_vector_type(8))) __bf16 bf16x8;
typedef __attribute__((ext_vector_type(4))) float f32x4;
typedef __attribute__((ext_vector_type(4))) unsigned u32x4;
typedef __attribute__((ext_vector_type(2))) unsigned u32x2;

static __device__ inline unsigned short f2bf(float x) {   // RNE
    union { float f; unsigned u; } v; v.f = x;
    unsigned r = v.u + 0x7FFFu + ((v.u >> 16) & 1u);
    return (unsigned short)(r >> 16);
}
static __device__ inline float bf2f(unsigned short h) {
    union { float f; unsigned u; } v; v.u = ((unsigned)h) << 16;
    return v.f;
}
static __device__ inline unsigned pk2bf(float a, float b) {
    return (unsigned)f2bf(a) | ((unsigned)f2bf(b) << 16);
}
static __device__ inline float fast_exp2(float x) {
#if __has_builtin(__builtin_amdgcn_exp2f)
    return __builtin_amdgcn_exp2f(x);
#else
    return exp2f(x);
#endif
}
static __device__ inline f32x4 mfma16(us8 a, us8 b, f32x4 c) {
    return __builtin_amdgcn_mfma_f32_16x16x32_bf16(
        __builtin_bit_cast(bf16x8, a), __builtin_bit_cast(bf16x8, b), c, 0, 0, 0);
}

// ---------- pre-pass: K -> bf16 row-major; V -> bf16 transposed per 64-tile ----------
__global__ __launch_bounds__(256)
void prep_kv(const float* __restrict__ K, const float* __restrict__ V,
             unsigned short* __restrict__ Kbf, unsigned short* __restrict__ Vtb)
{
    const int bx = (int)blockIdx.x, t = (int)threadIdx.x;
    __shared__ __align__(16) float Ls[64][130];
    if (bx < 512) {
        const size_t base = ((size_t)bx * 256 + t) * 8;
        float x[8];
        *(float4*)&x[0] = *(const float4*)(K + base);
        *(float4*)&x[4] = *(const float4*)(K + base + 4);
        u32x4 pk;
        #pragma unroll
        for (int j = 0; j < 4; ++j) pk[j] = pk2bf(x[2*j], x[2*j+1]);
        *(us8*)(Kbf + base) = __builtin_bit_cast(us8, pk);
    } else {
        // V transpose: block per (kvh, tile64): Vt[kvh][tile][128 dims][64 k]
        const int b2 = bx - 512, kvh = b2 >> 5, tile = b2 & 31;
        const float* vb = V + ((size_t)kvh * SEQ + tile * 64) * HEAD_DIM;
        #pragma unroll
        for (int i = 0; i < 8; ++i) {
            const int idx = t + i * 256;
            const int r = idx >> 5, c4 = idx & 31;
            *(float4*)&Ls[r][c4 * 4] = *(const float4*)(vb + (size_t)r * HEAD_DIM + c4 * 4);
        }
        __syncthreads();
        const int d = t & 127, kh = t >> 7;
        unsigned pk[16];
        #pragma unroll
        for (int j = 0; j < 16; ++j)
            pk[j] = pk2bf(Ls[kh * 32 + 2*j][d], Ls[kh * 32 + 2*j + 1][d]);
        unsigned short* dst = Vtb + ((size_t)(kvh * 32 + tile) * 128 + d) * 64 + kh * 32;
        #pragma unroll
        for (int blk = 0; blk < 4; ++blk)
            *(us8*)(dst + blk * 8) = *(us8*)&pk[blk * 4];
    }
}

// ---------- main: flash diff-attn, S^T MFMA, double-buffered async staging ----------
// smem: K dbuf 2x16384 | Vt dbuf 2x16384 | P 4x2304 = 74752 B -> 2 blocks/CU
#define KB0 0
#define KB1 16384
#define VB0 32768
#define VB1 49152
#define P_OFF 65536

__global__ __launch_bounds__(256, 2)
void diff_attn_mfma5(const float* __restrict__ Q,
                     const unsigned short* __restrict__ Kbf,
                     const unsigned short* __restrict__ Vtb,
                     float* __restrict__ Out)
{
    __shared__ __align__(16) unsigned char smem[74752];

    const int t    = (int)threadIdx.x;
    const int wv   = t >> 6;
    const int ln   = t & 63;
    const int l15  = ln & 15;
    const int quad = ln >> 4;
    const int mat  = wv >> 1;      // 0: softmax1 (dims 0..63), 1: softmax2 (dims 64..127)
    const int rfh  = wv & 1;       // rows rfh*16..+15 of the 32-row q-tile

    // grid 1024 = 16 h x 64 q-tiles(32 rows); idx pairing balances causal work
    const int bx  = (int)blockIdx.x;
    const int h   = bx & 15;
    const int idx = bx >> 4;                    // 0..63
    const int qt  = (idx < 32) ? idx : 95 - idx;
    const int kvh = h >> 2;
    const int q0  = qt * 32;
    const int nkt = (qt >> 1) + 1;

    // ---- Q fragment (B-operand layout: lane n=l15 q-row, k=quad*8+j), hi/lo split ----
    // scale folds 1/8 and log2(e): softmax uses raw 2^x
    us8 qhi[2], qlo[2];
    {
        const float* qr = Q + ((size_t)h * SEQ + q0 + rfh * 16 + l15) * HEAD_DIM + mat * 64;
        const float qscale = 0.125f * 1.44269504088896340736f;
        #pragma unroll
        for (int kc = 0; kc < 2; ++kc) {
            const int d0 = kc * 32 + quad * 8;
            float x[8];
            *(float4*)&x[0] = *(const float4*)(qr + d0);
            *(float4*)&x[4] = *(const float4*)(qr + d0 + 4);
            us8 hi8, lo8;
            #pragma unroll
            for (int j = 0; j < 8; ++j) {
                float xs = x[j] * qscale;
                unsigned short hb = f2bf(xs);
                hi8[j] = hb;
                lo8[j] = f2bf(xs - bf2f(hb));
            }
            qhi[kc] = hi8; qlo[kc] = lo8;
        }
    }

    f32x4 o[8];                    // O^T frags: dim = dt*16+quad*4+rg, q-row = l15
    #pragma unroll
    for (int i = 0; i < 8; ++i) o[i] = (f32x4)0.f;
    f32x4 rsv = (f32x4)0.f;        // row-sum partials (4 independent chains)

    const unsigned short* Kt0 = Kbf + (size_t)kvh * SEQ * HEAD_DIM;
    const unsigned short* Vt0 = Vtb + (size_t)kvh * 32 * 128 * 64;
    unsigned char* Pp = smem + P_OFF + wv * 2304;   // wave-private P [16][72] ushorts

    // async stage of tile kt into buffers at koff/voff (wave-uniform base + lane*16)
    auto issue = [&](int kt, int koff, int voff) {
        #pragma unroll
        for (int i = 0; i < 4; ++i) {
            const int L  = i * 256 + wv * 64 + ln;
            const int r  = L >> 4;
            const int ch = (L & 15) ^ (r & 15);
            const unsigned short* g = Kt0 + (size_t)(kt * 64 + r) * 128 + ch * 8;
            __builtin_amdgcn_global_load_lds(
                (const __attribute__((address_space(1))) unsigned*)g,
                (__attribute__((address_space(3))) unsigned*)(smem + koff + (i * 256 + wv * 64) * 16),
                16, 0, 0);
        }
        #pragma unroll
        for (int i = 0; i < 4; ++i) {
            const int L  = i * 256 + wv * 64 + ln;
            const int r  = L >> 3;
            const int ch = (L & 7) ^ (r & 7);
            const unsigned short* g = Vt0 + (size_t)(kt * 128 + r) * 64 + ch * 8;
            __builtin_amdgcn_global_load_lds(
                (const __attribute__((address_space(1))) unsigned*)g,
                (__attribute__((address_space(3))) unsigned*)(smem + voff + (i * 256 + wv * 64) * 16),
                16, 0, 0);
        }
    };

    issue(0, KB0, VB0);   // prologue: first tile into buffer 0

    for (int kt = 0; kt < nkt; ++kt) {
        const int cur = kt & 1;
        __syncthreads();   // drains prefetch (issued last iter -> buf[cur] ready);
                           // all waves done reading buf[cur^1]

        if (kt + 1 < nkt) issue(kt + 1, cur ? KB0 : KB1, cur ? VB0 : VB1);

        const unsigned char* kbase = smem + (cur ? KB1 : KB0);
        const unsigned char* vbase = smem + (cur ? VB1 : VB0);
        const bool lastkt = (kt == nkt - 1);

        // ---- scores S^T = K . Q^T + exp2 + pack P ----
        #pragma unroll
        for (int c4 = 0; c4 < 4; ++c4) {
            f32x4 s = (f32x4)0.f;
            #pragma unroll
            for (int kc = 0; kc < 2; ++kc) {
                const int r  = c4 * 16 + l15;
                const int ch = (mat * 8 + kc * 4 + quad) ^ l15;
                us8 ak = *(const us8*)(kbase + r * 256 + ch * 16);
                s = mfma16(ak, qhi[kc], s);
                s = mfma16(ak, qlo[kc], s);
            }
            float ev[4];
            if (lastkt) {            // only the diagonal tile can be masked (uniform branch)
                const int kg0 = kt * 64 + c4 * 16 + quad * 4;
                const int qg  = q0 + rfh * 16 + l15;
                #pragma unroll
                for (int rg = 0; rg < 4; ++rg)
                    ev[rg] = ((kg0 + rg) <= qg) ? fast_exp2(s[rg]) : 0.f;
            } else {
                #pragma unroll
                for (int rg = 0; rg < 4; ++rg)
                    ev[rg] = fast_exp2(s[rg]);
            }
            unsigned tr[4];
            #pragma unroll
            for (int rg = 0; rg < 4; ++rg) {
                tr[rg] = __builtin_bit_cast(unsigned, ev[rg]) & 0xffff0000u;
                rsv[rg] += __builtin_bit_cast(float, tr[rg]);   // denom from quantized P
            }
            u32x2 pw;
            pw[0] = (tr[0] >> 16) | tr[1];
            pw[1] = (tr[2] >> 16) | tr[3];
            *(u32x2*)(Pp + l15 * 144 + c4 * 32 + quad * 8) = pw;
        }

        // wave-private P: drain own LDS ops only, no block barrier
        asm volatile("s_waitcnt lgkmcnt(0)" ::: "memory");

        // ---- PV: O^T = V^T . P^T (A = Vt frag, B = P frag) ----
        #pragma unroll
        for (int c2 = 0; c2 < 2; ++c2) {
            us8 bp = *(const us8*)(Pp + l15 * 144 + c2 * 64 + quad * 16);
            #pragma unroll
            for (int dt = 0; dt < 8; ++dt) {
                const int r  = dt * 16 + l15;
                const int ch = (c2 * 4 + quad) ^ (r & 7);
                us8 av = *(const us8*)(vbase + r * 128 + ch * 16);
                o[dt] = mfma16(av, bp, o[dt]);
            }
        }
    }

    __syncthreads();   // all LDS reads done; smem reusable for combine

    // row sum: combine 4 partials, reduce across the 4 quads
    float rs = (rsv[0] + rsv[1]) + (rsv[2] + rsv[3]);
    rs += __shfl_xor(rs, 16, 64);
    rs += __shfl_xor(rs, 32, 64);
    const float inv = 1.0f / rs;

    float* Cb = (float*)smem;   // [32 rows][132] combine buffer (16896 B)
    if (mat == 1) {
        #pragma unroll
        for (int dt = 0; dt < 8; ++dt) {
            f32x4 v;
            #pragma unroll
            for (int rg = 0; rg < 4; ++rg) v[rg] = o[dt][rg] * inv;
            *(f32x4*)(Cb + (rfh * 16 + l15) * 132 + dt * 16 + quad * 4) = v;
        }
    }
    __syncthreads();
    if (mat == 0) {
        float* ob = Out + ((size_t)h * SEQ + q0 + rfh * 16 + l15) * HEAD_DIM;
        #pragma unroll
        for (int dt = 0; dt < 8; ++dt) {
            const float* cb = Cb + (rfh * 16 + l15) * 132 + dt * 16 + quad * 4;
            float4 r;
            r.x = 0.2f * (o[dt][0] * inv) - 0.16f * cb[0];
            r.y = 0.2f * (o[dt][1] * inv) - 0.16f * cb[1];
            r.z = 0.2f * (o[dt][2] * inv) - 0.16f * cb[2];
            r.w = 0.2f * (o[dt][3] * inv) - 0.16f * cb[3];
            *(float4*)(ob + dt * 16 + quad * 4) = r;
        }
    }
}

extern "C" void kernel_launch(void* const* d_in, const int* in_sizes, int n_in,
                              void* d_out, int out_size, void* d_ws, size_t ws_size,
                              hipStream_t stream) {
    const float* Q = (const float*)d_in[0];
    const float* K = (const float*)d_in[1];
    const float* V = (const float*)d_in[2];
    float* Out = (float*)d_out;

    unsigned short* Kbf = (unsigned short*)d_ws;             // 2 MB
    unsigned short* Vtb = Kbf + (size_t)4 * SEQ * HEAD_DIM;  // 2 MB

    prep_kv<<<640, 256, 0, stream>>>(K, V, Kbf, Vtb);
    diff_attn_mfma5<<<1024, 256, 0, stream>>>(Q, Kbf, Vtb, Out);
}